// Round 16
// baseline (27.870 us; speedup 1.0000x reference)
//
#include <hip/hip_runtime.h>
#include <math.h>

#define DIM 1024
#define KK 7
#define DIL 2
#define BATCH 16384
#define NEG 0.01f
#define ROWS 8      // rows per block, grid = 2048
#define SLOT 320    // floats per row slot: 256 main + 12 halo + 52 junk zone
                    // (gload_lds halo ALWAYS writes 64 floats at slot+256 ->
                    //  [256,320) must be inside the slot; R15's SLOT=272
                    //  overflowed into the next slot = the correctness bug)
#define WSTR (2 * 2 * SLOT)   // per-wave LDS floats: 2 pair-slots x 2 rows

// Direct global->LDS DMA; no destination VGPR -> un-sinkable; vmcnt-tracked.
__device__ __forceinline__ void gload_lds16(const float* g, float* l) {
    __builtin_amdgcn_global_load_lds(
        (const __attribute__((address_space(1))) void*)g,
        (__attribute__((address_space(3))) void*)l, 16, 0, 0);
}
__device__ __forceinline__ void gload_lds4(const float* g, float* l) {
    __builtin_amdgcn_global_load_lds(
        (const __attribute__((address_space(1))) void*)g,
        (__attribute__((address_space(3))) void*)l, 4, 0, 0);
}

// ---------------------------------------------------------------------------
// R13 structure, rows processed in PAIRS (wait-granularity experiment):
// 4 wait-points per wave instead of 8, 2 KB consumed per wake, counted vmcnt
// {4,6,6,2} (position-derived: 4 load instrs/pair, 2 stores/pair, in-order
// retirement). Halo clamp (lanes>=12 re-read the same 64B line, full exec),
// junk contained in slot[268,320). Wave 3 halo -> dummy sink; its read-halo
// [256,272) zeroed once.
// ---------------------------------------------------------------------------
__global__ __launch_bounds__(256)
void cnn_flow_fused(const float* __restrict__ x,
                    const float* __restrict__ wgt,
                    const float* __restrict__ bias,
                    const float* __restrict__ lmbd,
                    float* __restrict__ out,
                    float* __restrict__ logdet) {
    const int t    = threadIdx.x;
    const int wv   = t >> 6;
    const int lane = t & 63;
    const int base = t << 2;                  // global feature = wv*256+lane*4
    const int row0 = blockIdx.x * ROWS;

    __shared__ float sx[4 * WSTR];            // 20480 B staging
    __shared__ float red[ROWS][4];            // per-row wave partials
    __shared__ float dummy[64];               // sink for wave 3's halo loads

    // wave 3: zero the read-halo region of its 4 row slots once (never gloaded)
    if (wv == 3 && lane < 16) {
#pragma unroll
        for (int s = 0; s < 4; ++s)
            sx[3 * WSTR + s * SLOT + 256 + lane] = 0.0f;
    }

    const float* growbase = x + (size_t)row0 * DIM;
    const float* gmain = growbase + (wv << 8) + (lane << 2);   // 16B/lane
    // halo: lanes >=12 clamp to float 11 -> same 64B line, full exec mask
    const int hl = (lane < 12) ? lane : 11;
    const float* ghalo = growbase + ((wv < 3) ? (wv << 8) + 256 : 0) + hl;

    auto issue_pair = [&](int p) {            // rows 2p, 2p+1 -> pair-slot p&1
        float* s0 = sx + wv * WSTR + (p & 1) * (2 * SLOT);
        gload_lds16(gmain + (2 * p) * DIM, s0 + (lane << 2));
        gload_lds4(ghalo + (2 * p) * DIM, ((wv < 3) ? s0 + 256 : dummy) + lane);
        gload_lds16(gmain + (2 * p + 1) * DIM, s0 + SLOT + (lane << 2));
        gload_lds4(ghalo + (2 * p + 1) * DIM,
                   ((wv < 3) ? s0 + SLOT + 256 : dummy) + lane);
    };

    // prologue: pairs 0,1 in flight (8 load instrs, 4 KB/wave)
    issue_pair(0);
    issue_pair(1);

    // scalar params + per-feature tables: computed while prologue loads fly
    float w[KK];
#pragma unroll
    for (int k = 0; k < KK; ++k) w[k] = wgt[k];
    const float w0 = w[0];
    const float bs = bias[0];

    float sc[4], lp[4], ln[4];
    {
        float4 lm = *reinterpret_cast<const float4*>(lmbd + base);
        float lms[4] = {lm.x, lm.y, lm.z, lm.w};
        const float inv = (w0 != 0.0f) ? (-1.0f / w0) : 0.0f;
#pragma unroll
        for (int i = 0; i < 4; ++i) {
            float l  = lms[i];
            float sp = fmaxf(l, 0.0f) + log1pf(expf(-fabsf(l)));  // softplus
            float scale;
            if (w0 == 0.0f)      scale = l;
            else if (w0 > 0.0f)  scale = inv + sp;
            else                 scale = inv - sp;
            sc[i] = scale;
            lp[i] = logf(fabsf(fmaf(scale,       w0, 1.0f)));   // act_grad=1
            ln[i] = logf(fabsf(fmaf(NEG * scale, w0, 1.0f)));   // act_grad=NEG
        }
    }

#pragma unroll
    for (int p = 0; p < ROWS / 2; ++p) {
        // counted wait for pair p's 4 load instrs; newer ops stay in flight.
        if      (p == 0)            asm volatile("s_waitcnt vmcnt(4)" ::: "memory");
        else if (p == ROWS / 2 - 1) asm volatile("s_waitcnt vmcnt(2)" ::: "memory");
        else                        asm volatile("s_waitcnt vmcnt(6)" ::: "memory");

        const float* s0 = sx + wv * WSTR + (p & 1) * (2 * SLOT);
#pragma unroll
        for (int j = 0; j < 2; ++j) {
            const int r = 2 * p + j;
            const float* srow = s0 + j * SLOT + (lane << 2);
            float xv[16];
#pragma unroll
            for (int q = 0; q < 4; ++q) {     // 4x ds_read_b128, wave-private
                float4 v = *reinterpret_cast<const float4*>(srow + 4 * q);
                xv[4 * q + 0] = v.x; xv[4 * q + 1] = v.y;
                xv[4 * q + 2] = v.z; xv[4 * q + 3] = v.w;
            }

            float ld_acc = 0.0f;
            float o[4];
#pragma unroll
            for (int i = 0; i < 4; ++i) {
                float conv = bs;
#pragma unroll
                for (int kk = 0; kk < KK; ++kk)
                    conv = fmaf(xv[i + DIL * kk], w[kk], conv);
                bool pos  = (conv >= 0.0f);
                float act = pos ? conv : NEG * conv;
                o[i]      = fmaf(act, sc[i], xv[i]);
                ld_acc   += pos ? lp[i] : ln[i];
            }
            *reinterpret_cast<float4*>(out + (size_t)(row0 + r) * DIM + base) =
                make_float4(o[0], o[1], o[2], o[3]);

            // wave shuffle reduce (hidden per R6 A/B); park per-wave partial
#pragma unroll
            for (int off = 32; off > 0; off >>= 1)
                ld_acc += __shfl_down(ld_acc, off, 64);
            if (lane == 0) red[r][wv] = ld_acc;
        }

        // refill the slot we just freed with pair p+2
        if (p + 2 < ROWS / 2) issue_pair(p + 2);
    }

    __syncthreads();                          // only barrier in the kernel
    if (t < ROWS)
        logdet[row0 + t] = (red[t][0] + red[t][1]) + (red[t][2] + red[t][3]);
}

extern "C" void kernel_launch(void* const* d_in, const int* in_sizes, int n_in,
                              void* d_out, int out_size, void* d_ws, size_t ws_size,
                              hipStream_t stream) {
    const float* x    = (const float*)d_in[0];
    const float* wgt  = (const float*)d_in[1];
    const float* bias = (const float*)d_in[2];
    const float* lmbd = (const float*)d_in[3];
    float* out    = (float*)d_out;                    // (BATCH, DIM)
    float* logdet = out + (size_t)BATCH * DIM;        // (BATCH,)

    cnn_flow_fused<<<BATCH / ROWS, 256, 0, stream>>>(x, wgt, bias, lmbd, out, logdet);
}

// Round 17
// 27.357 us; speedup vs baseline: 1.0187x; 1.0187x over previous
//
#include <hip/hip_runtime.h>
#include <math.h>

#define DIM 1024
#define KK 7
#define DIL 2
#define BATCH 16384
#define NEG 0.01f
#define ROWS 8      // rows per block, grid = 2048 (8 blocks/CU, 32 waves/CU)

typedef float f4v __attribute__((ext_vector_type(4)));

// Inline-asm global load: opaque to the scheduler -> CANNOT be sunk next to
// its use (the failure mode of every register-prefetch variant, R5/R8).
// SGPR base + 32-bit voffset form (saves VGPRs vs 64-bit per-lane address).
__device__ __forceinline__ f4v gload4s(unsigned voff_bytes, const float* sbase) {
    f4v r;
    asm volatile("global_load_dwordx4 %0, %1, %2"
                 : "=v"(r) : "v"(voff_bytes), "s"(sbase) : "memory");
    return r;
}

// ---------------------------------------------------------------------------
// Register-direct streaming, forced pipeline. No LDS in the hot loop (tests
// the last structural difference vs the 6.29 TB/s copy ubench: the
// global->LDS->ds_read round-trip). Per thread: 4 features, 16-float window
// via 4 overlapping asm dwordx4 loads (redundancy = same-block L1 hits, L2
// traffic 1x — verified FETCH 32.9MB in R5). Depth-1 issue-ahead: row r+1's
// loads issued BEFORE row r's wait. Counted vmcnt by position (4 loads + 1
// store per row, in-order retirement): {4,5,5,5,5,5,5,1}; sched_barrier(0)
// after each wait (rule #18: compiler hoists reg-only consumers past asm
// waitcnt otherwise). lmbd is asm-loaded too so vmcnt positions stay exact.
// Tail (t>=253): voffsets clamped to row end, out-of-range window floats
// zeroed (3 threads diverge, wave 3 only).
// ---------------------------------------------------------------------------
__global__ __launch_bounds__(256)
void cnn_flow_fused(const float* __restrict__ x,
                    const float* __restrict__ wgt,
                    const float* __restrict__ bias,
                    const float* __restrict__ lmbd,
                    float* __restrict__ out,
                    float* __restrict__ logdet) {
    const int t    = threadIdx.x;
    const int wv   = t >> 6;
    const int lane = t & 63;
    const int base = t << 2;                  // 4 features per thread
    const int row0 = blockIdx.x * ROWS;

    __shared__ float red[ROWS][4];            // per-row wave partials (epilogue)

    // scalar params first (uniform -> s_load, lgkmcnt; older than all asm VMEM)
    float w[KK];
#pragma unroll
    for (int k = 0; k < KK; ++k) w[k] = wgt[k];
    const float w0 = w[0];
    const float bs = bias[0];

    // clamped voffsets (bytes), computed once: off_j = 4*min(base+4j, DIM-4)
    unsigned voff[4];
#pragma unroll
    for (int j = 0; j < 4; ++j) {
        int f = base + 4 * j;
        voff[j] = 4u * (unsigned)((f <= DIM - 4) ? f : DIM - 4);
    }

    // VMEM position 0: lmbd window. Positions 1..4: row 0.
    f4v lm4 = gload4s(4u * (unsigned)base, lmbd);
    f4v q[2][4];
    {
        const float* r0 = x + (size_t)row0 * DIM;
        q[0][0] = gload4s(voff[0], r0);
        q[0][1] = gload4s(voff[1], r0);
        q[0][2] = gload4s(voff[2], r0);
        q[0][3] = gload4s(voff[3], r0);
    }
    // retire lm4 (4 newer: row-0 loads), keep row 0 in flight
    asm volatile("s_waitcnt vmcnt(4)" ::: "memory");
    __builtin_amdgcn_sched_barrier(0);

    // per-feature tables (trans ops overlap row-0 flight)
    float sc[4], lp[4], ln[4];
    {
        float lms[4] = {lm4.x, lm4.y, lm4.z, lm4.w};
        const float inv = (w0 != 0.0f) ? (-1.0f / w0) : 0.0f;
#pragma unroll
        for (int i = 0; i < 4; ++i) {
            float l  = lms[i];
            float sp = fmaxf(l, 0.0f) + log1pf(expf(-fabsf(l)));  // softplus
            float scale;
            if (w0 == 0.0f)      scale = l;
            else if (w0 > 0.0f)  scale = inv + sp;
            else                 scale = inv - sp;
            sc[i] = scale;
            lp[i] = logf(fabsf(fmaf(scale,       w0, 1.0f)));   // act_grad=1
            ln[i] = logf(fabsf(fmaf(NEG * scale, w0, 1.0f)));   // act_grad=NEG
        }
    }

#pragma unroll
    for (int r = 0; r < ROWS; ++r) {
        const int cb = r & 1, nb = cb ^ 1;
        if (r + 1 < ROWS) {                   // issue row r+1 BEFORE waiting
            const float* rn = x + (size_t)(row0 + r + 1) * DIM;
            q[nb][0] = gload4s(voff[0], rn);
            q[nb][1] = gload4s(voff[1], rn);
            q[nb][2] = gload4s(voff[2], rn);
            q[nb][3] = gload4s(voff[3], rn);
        }
        // counted wait: row r's 4 loads retired; newer loads/stores in flight.
        // Positions: {4,5,5,5,5,5,5,1}.
        if      (r == 0)        asm volatile("s_waitcnt vmcnt(4)" ::: "memory");
        else if (r == ROWS - 1) asm volatile("s_waitcnt vmcnt(1)" ::: "memory");
        else                    asm volatile("s_waitcnt vmcnt(5)" ::: "memory");
        __builtin_amdgcn_sched_barrier(0);    // rule #18: pin consumers after wait

        float xv[16];
        xv[0]  = q[cb][0].x; xv[1]  = q[cb][0].y; xv[2]  = q[cb][0].z; xv[3]  = q[cb][0].w;
        xv[4]  = q[cb][1].x; xv[5]  = q[cb][1].y; xv[6]  = q[cb][1].z; xv[7]  = q[cb][1].w;
        xv[8]  = q[cb][2].x; xv[9]  = q[cb][2].y; xv[10] = q[cb][2].z; xv[11] = q[cb][2].w;
        xv[12] = q[cb][3].x; xv[13] = q[cb][3].y; xv[14] = q[cb][3].z; xv[15] = q[cb][3].w;
        if (base > DIM - 16) {                // 3 threads/block: zero past-DIM taps
#pragma unroll
            for (int j = 4; j < 16; ++j)
                if (base + j >= DIM) xv[j] = 0.0f;
        }

        float ld_acc = 0.0f;
        float o[4];
#pragma unroll
        for (int i = 0; i < 4; ++i) {
            float conv = bs;
#pragma unroll
            for (int kk = 0; kk < KK; ++kk)
                conv = fmaf(xv[i + DIL * kk], w[kk], conv);
            bool pos  = (conv >= 0.0f);
            float act = pos ? conv : NEG * conv;
            o[i]      = fmaf(act, sc[i], xv[i]);
            ld_acc   += pos ? lp[i] : ln[i];
        }
        *reinterpret_cast<float4*>(out + (size_t)(row0 + r) * DIM + base) =
            make_float4(o[0], o[1], o[2], o[3]);   // VMEM position: 1 store/row

        // wave shuffle reduce (lgkm pipe, hidden per R6 A/B); park partial
#pragma unroll
        for (int off = 32; off > 0; off >>= 1)
            ld_acc += __shfl_down(ld_acc, off, 64);
        if (lane == 0) red[r][wv] = ld_acc;
    }

    __syncthreads();                          // epilogue only
    if (t < ROWS)
        logdet[row0 + t] = (red[t][0] + red[t][1]) + (red[t][2] + red[t][3]);
}

extern "C" void kernel_launch(void* const* d_in, const int* in_sizes, int n_in,
                              void* d_out, int out_size, void* d_ws, size_t ws_size,
                              hipStream_t stream) {
    const float* x    = (const float*)d_in[0];
    const float* wgt  = (const float*)d_in[1];
    const float* bias = (const float*)d_in[2];
    const float* lmbd = (const float*)d_in[3];
    float* out    = (float*)d_out;                    // (BATCH, DIM)
    float* logdet = out + (size_t)BATCH * DIM;        // (BATCH,)

    cnn_flow_fused<<<BATCH / ROWS, 256, 0, stream>>>(x, wgt, bias, lmbd, out, logdet);
}

// Round 18
// 26.595 us; speedup vs baseline: 1.0479x; 1.0286x over previous
//
#include <hip/hip_runtime.h>
#include <math.h>

#define DIM 1024
#define KK 7
#define DIL 2
#define BATCH 16384
#define NEG 0.01f
#define ROWS 8      // rows per block, grid = 2048 (= 8 blocks/CU exactly, no tail)
#define NBUF 3      // per-wave row slots (depth-2 prefetch + current)
#define DEPTH 2     // rows issued ahead
#define SLOT 320    // floats per slot: 256 main + halo/junk region (reads [0,268);
                    // gload halo ALWAYS writes 64 floats at +256 -> [256,320) in-slot)

// Direct global->LDS DMA; no destination VGPR -> un-sinkable; vmcnt-tracked.
__device__ __forceinline__ void gload_lds16(const float* g, float* l) {
    __builtin_amdgcn_global_load_lds(
        (const __attribute__((address_space(1))) void*)g,
        (__attribute__((address_space(3))) void*)l, 16, 0, 0);
}
__device__ __forceinline__ void gload_lds4(const float* g, float* l) {
    __builtin_amdgcn_global_load_lds(
        (const __attribute__((address_space(1))) void*)g,
        (__attribute__((address_space(3))) void*)l, 4, 0, 0);
}

// ---------------------------------------------------------------------------
// BEST KERNEL (R13, 26.24 us — final). Barrier-free per-wave pipelines:
// each wave stages its own 256-float segment + halo per row into private LDS
// slots (window reads never cross waves -> no hot-loop s_barrier), counted
// per-wave s_waitcnt vmcnt {4,5,6,6,6,6,4,2} keeps 2 rows of reads + stores
// in flight continuously. Halo: all 64 lanes active, lanes >=12 clamp to the
// same 64B line (never exec-predicate gload_lds — R12 lesson); wave 3's halo
// goes to a dummy sink, its read-halo zeroed once. Logdet: in-loop wave
// shuffle reduce (hidden), one barrier at block end.
// Ledger: occupancy/depth/barriers/vmcnt-granularity/nt-store/halo-traffic/
// VALU-packing/LDS-roundtrip all tested; 5 structures converge 26.2-27.9 us
// = ~81% of the pure-copy ceiling on a 2:1 W:R mixed stream. Roofline.
// ---------------------------------------------------------------------------
__global__ __launch_bounds__(256)
void cnn_flow_fused(const float* __restrict__ x,
                    const float* __restrict__ wgt,
                    const float* __restrict__ bias,
                    const float* __restrict__ lmbd,
                    float* __restrict__ out,
                    float* __restrict__ logdet) {
    const int t    = threadIdx.x;
    const int wv   = t >> 6;
    const int lane = t & 63;
    const int base = t << 2;                  // global feature = wv*256+lane*4
    const int row0 = blockIdx.x * ROWS;

    __shared__ float sx[4 * NBUF * SLOT];     // 15360 B staging
    __shared__ float red[ROWS][4];            // per-row wave partials
    __shared__ float dummy[64];               // sink for wave 3's halo loads

    // wave 3: zero the read-halo region of its own slots once (never gloaded)
    if (wv == 3 && lane < 16) {
#pragma unroll
        for (int s = 0; s < NBUF; ++s)
            sx[(3 * NBUF + s) * SLOT + 256 + lane] = 0.0f;
    }

    const float* growbase = x + (size_t)row0 * DIM;
    const float* gmain = growbase + (wv << 8) + (lane << 2);   // 16B/lane
    // halo: lanes >=12 clamp to float 11 -> same 64B line, full exec mask
    const int hl = (lane < 12) ? lane : 11;
    const float* ghalo = growbase + ((wv < 3) ? (wv << 8) + 256 : 0) + hl;

    auto issue_row = [&](int r) {
        float* slot = sx + (wv * NBUF + (r % NBUF)) * SLOT;
        gload_lds16(gmain + r * DIM, slot + (lane << 2));
        gload_lds4(ghalo + r * DIM, ((wv < 3) ? slot + 256 : dummy) + lane);
    };

    // prologue: rows 0,1 in flight
    issue_row(0);
    issue_row(1);

    // scalar params + per-feature tables: computed while prologue loads fly
    float w[KK];
#pragma unroll
    for (int k = 0; k < KK; ++k) w[k] = wgt[k];
    const float w0 = w[0];
    const float bs = bias[0];

    float sc[4], lp[4], ln[4];
    {
        float4 lm = *reinterpret_cast<const float4*>(lmbd + base);
        float lms[4] = {lm.x, lm.y, lm.z, lm.w};
        const float inv = (w0 != 0.0f) ? (-1.0f / w0) : 0.0f;
#pragma unroll
        for (int i = 0; i < 4; ++i) {
            float l  = lms[i];
            float sp = fmaxf(l, 0.0f) + log1pf(expf(-fabsf(l)));  // softplus
            float scale;
            if (w0 == 0.0f)      scale = l;
            else if (w0 > 0.0f)  scale = inv + sp;
            else                 scale = inv - sp;
            sc[i] = scale;
            lp[i] = logf(fabsf(fmaf(scale,       w0, 1.0f)));   // act_grad=1
            ln[i] = logf(fabsf(fmaf(NEG * scale, w0, 1.0f)));   // act_grad=NEG
        }
    }

#pragma unroll
    for (int r = 0; r < ROWS; ++r) {
        if (r + DEPTH < ROWS) issue_row(r + DEPTH);

        // counted per-wave wait: row r's 2 load instrs retired, newer loads +
        // stores stay in flight. Position-derived: {4,5,6,6,6,6,4,2}.
        if      (r == 0) asm volatile("s_waitcnt vmcnt(4)" ::: "memory");
        else if (r == 1) asm volatile("s_waitcnt vmcnt(5)" ::: "memory");
        else if (r == 6) asm volatile("s_waitcnt vmcnt(4)" ::: "memory");
        else if (r == 7) asm volatile("s_waitcnt vmcnt(2)" ::: "memory");
        else             asm volatile("s_waitcnt vmcnt(6)" ::: "memory");

        const float* srow = sx + (wv * NBUF + (r % NBUF)) * SLOT + (lane << 2);
        float xv[16];
#pragma unroll
        for (int j = 0; j < 4; ++j) {         // 4x ds_read_b128, wave-private
            float4 v = *reinterpret_cast<const float4*>(srow + 4 * j);
            xv[4 * j + 0] = v.x; xv[4 * j + 1] = v.y;
            xv[4 * j + 2] = v.z; xv[4 * j + 3] = v.w;
        }

        float ld_acc = 0.0f;
        float o[4];
#pragma unroll
        for (int i = 0; i < 4; ++i) {
            float conv = bs;
#pragma unroll
            for (int kk = 0; kk < KK; ++kk)
                conv = fmaf(xv[i + DIL * kk], w[kk], conv);
            bool pos  = (conv >= 0.0f);
            float act = pos ? conv : NEG * conv;
            o[i]      = fmaf(act, sc[i], xv[i]);
            ld_acc   += pos ? lp[i] : ln[i];
        }
        *reinterpret_cast<float4*>(out + (size_t)(row0 + r) * DIM + base) =
            make_float4(o[0], o[1], o[2], o[3]);

        // wave shuffle reduce (hidden); park per-wave partial, fire-and-forget
#pragma unroll
        for (int off = 32; off > 0; off >>= 1)
            ld_acc += __shfl_down(ld_acc, off, 64);
        if (lane == 0) red[r][wv] = ld_acc;
    }

    __syncthreads();                          // only barrier in the kernel
    if (t < ROWS)
        logdet[row0 + t] = (red[t][0] + red[t][1]) + (red[t][2] + red[t][3]);
}

extern "C" void kernel_launch(void* const* d_in, const int* in_sizes, int n_in,
                              void* d_out, int out_size, void* d_ws, size_t ws_size,
                              hipStream_t stream) {
    const float* x    = (const float*)d_in[0];
    const float* wgt  = (const float*)d_in[1];
    const float* bias = (const float*)d_in[2];
    const float* lmbd = (const float*)d_in[3];
    float* out    = (float*)d_out;                    // (BATCH, DIM)
    float* logdet = out + (size_t)BATCH * DIM;        // (BATCH,)

    cnn_flow_fused<<<BATCH / ROWS, 256, 0, stream>>>(x, wgt, bias, lmbd, out, logdet);
}